// Round 13
// baseline (127.816 us; speedup 1.0000x reference)
//
#include <hip/hip_runtime.h>
#include <hip/hip_fp16.h>

#define OUT_H 512
#define OUT_W 512
#define BATCH 64
#define CHANS 3

// Per-wave window: 16x16 output tile -> source span 15(|c|+|s|)+2 <= 23.3 -> 24x24 px.
// f16 planes row-interleaved in the wave's private slice: A{c0,c1} at 51r+lx,
// B{c2,0} at 51r+25+lx. All 8 corner dwords of a pixel sit at ONE vaddr +
// {0,1, 25,26, 51,52, 76,77} -> 4x ds_read2_b32. Row stride 51 odd -> gcd(51,32)=1.
#define WIN   24
#define RST   51
#define BOFF  25
#define WSLOT 1224               // max touched slot 1221; pad to mult of 8
#define IDXMAX (RST*22 + 22)     // 1144: max read 1144+77=1221 < 1224

__global__ __launch_bounds__(256) void st_bilinear_kernel(
    const float* __restrict__ U,      // [B, H, W, C] f32
    const float* __restrict__ theta,  // [B, 1]
    float* __restrict__ out)          // [B, H, W, C] f32
{
    __shared__ __align__(16) unsigned int smf[4 * WSLOT];   // 19584 B -> 8 blocks/CU

    // XCD-aware remap: XCD k gets images [k*8, k*8+8) (3.1 MB image fits 4 MB L2).
    int blk  = blockIdx.x;
    int lblk = (blk & 7) * 2048 + (blk >> 3);   // 16384 blocks

    int b   = lblk >> 8;                // image (uniform per block)
    int rem = lblk & 255;               // 16x16 quads of 32x32 px per image
    int qr  = rem >> 4;
    int qc  = rem & 15;

    int tid  = threadIdx.x;
    int wid  = tid >> 6;                // wave id 0..3 -> 16x16 tile within quad
    int lane = tid & 63;

    int i0 = (qr << 5) + ((wid >> 1) << 4);   // wave's output tile origin
    int j0 = (qc << 5) + ((wid & 1) << 4);

    unsigned int* smw = smf + wid * WSLOT;    // wave-private slice: NO barrier needed

    float tt = theta[__builtin_amdgcn_readfirstlane(b)];
    float s, c;
    __sincosf(tt, &s, &c);

    // x = xb0 + c*jl - s*il ; y = yb0 + s*jl + c*il  ((2/511)*255.5 == 1)
    const float scale = 2.0f / 511.0f;
    float gx0 = (float)j0 * scale - 1.0f;
    float gy0 = (float)i0 * scale - 1.0f;
    float xb0 = (c * gx0 - s * gy0 + 1.0f) * 255.5f;
    float yb0 = (s * gx0 + c * gy0 + 1.0f) * 255.5f;

    // Source bbox of the 16x16 tile (wave-uniform -> uniform branches).
    float xmin = xb0 + fminf(0.0f, 15.0f * c) + fminf(0.0f, -15.0f * s);
    float ymin = yb0 + fminf(0.0f, 15.0f * s) + fminf(0.0f,  15.0f * c);
    float xmax = xb0 + fmaxf(0.0f, 15.0f * c) + fmaxf(0.0f, -15.0f * s);
    float ymax = yb0 + fmaxf(0.0f, 15.0f * s) + fmaxf(0.0f,  15.0f * c);

    int bx0 = min(max((int)floorf(xmin), 0), OUT_W - 1);
    int by0 = min(max((int)floorf(ymin), 0), OUT_H - 1);
    int bx = min(bx0, OUT_W - WIN);     // 24x24 window always fully in-image
    int by = min(by0, OUT_H - WIN);

    // Interior: every px has ix,iy in [0,509] -> no idx clamp, no valid mask.
    bool interior = (xmin >= 0.0f) & (xmax < 510.0f) &
                    (ymin >= 0.0f) & (ymax < 510.0f);

    const float* Ub = U + (size_t)b * (OUT_H * OUT_W * CHANS);
    const float* gb = Ub + ((size_t)by * OUT_W + bx) * CHANS;
    bool origin = (b == 0) & (bx == 0) & (by == 0);   // only window whose -4B load underflows

    // ---- staging: 576 px = 9/lane, overlapping dwordx4 shifted 4B back so
    // {c0,c1,c2} = .y.z.w. Two chunks (5+4) cap VGPR. Writes: ds_write2_b32
    // at {slot, slot+25}, lane-stride 1 -> conflict-free. ----
    if (!origin) {
        float4 v0[5];
#pragma unroll
        for (int k = 0; k < 5; ++k) {
            unsigned q = (unsigned)lane + 64u * k;
            unsigned r = q / 24u, lx = q - r * 24u;
            v0[k] = *(const float4*)(gb + (size_t)r * (OUT_W * CHANS) + lx * 3u - 1);
        }
#pragma unroll
        for (int k = 0; k < 5; ++k) {
            unsigned q = (unsigned)lane + 64u * k;
            unsigned r = q / 24u, lx = q - r * 24u;
            float4 v = v0[k];
            __half2 hA = __floats2half2_rn(v.y, v.z);
            __half2 hB = __floats2half2_rn(v.w, 0.0f);
            unsigned slot = RST * r + lx;
            smw[slot]        = *(const unsigned int*)&hA;
            smw[slot + BOFF] = *(const unsigned int*)&hB;
        }
        float4 v1[4];
#pragma unroll
        for (int k = 0; k < 4; ++k) {
            unsigned q = (unsigned)lane + 64u * (k + 5);
            unsigned r = q / 24u, lx = q - r * 24u;
            v1[k] = *(const float4*)(gb + (size_t)r * (OUT_W * CHANS) + lx * 3u - 1);
        }
#pragma unroll
        for (int k = 0; k < 4; ++k) {
            unsigned q = (unsigned)lane + 64u * (k + 5);
            unsigned r = q / 24u, lx = q - r * 24u;
            float4 v = v1[k];
            __half2 hA = __floats2half2_rn(v.y, v.z);
            __half2 hB = __floats2half2_rn(v.w, 0.0f);
            unsigned slot = RST * r + lx;
            smw[slot]        = *(const unsigned int*)&hA;
            smw[slot + BOFF] = *(const unsigned int*)&hB;
        }
    } else {
#pragma unroll
        for (int k = 0; k < 9; ++k) {
            unsigned q = (unsigned)lane + 64u * k;
            unsigned r = q / 24u, lx = q - r * 24u;
            const float* p = gb + (size_t)r * (OUT_W * CHANS) + lx * 3u;
            float2 ab = *(const float2*)p;
            float  cc = p[2];
            __half2 hA = __floats2half2_rn(ab.x, ab.y);
            __half2 hB = __floats2half2_rn(cc, 0.0f);
            unsigned slot = RST * r + lx;
            smw[slot]        = *(const unsigned int*)&hA;
            smw[slot + BOFF] = *(const unsigned int*)&hB;
        }
    }
    // NO __syncthreads: same wave wrote this slice; in-wave lgkmcnt ordering
    // guarantees read-after-write.

    // ---- compute: lane -> 4 consecutive px in one row of the 16x16 tile ----
    int il  = lane >> 2;                // 0..15
    int jb2 = (lane & 3) << 2;          // 0,4,8,12
    float xr = xb0 + c * (float)jb2 - s * (float)il;
    float yr = yb0 + s * (float)jb2 + c * (float)il;
    int Koff = by * RST + bx;

    float o[12];
#pragma unroll
    for (int p = 0; p < 4; ++p) {
        float x = fmaf(c, (float)p, xr);
        float y = fmaf(s, (float)p, yr);
        int ix = __float2int_rd(x);
        int iy = __float2int_rd(y);
        float fx = x - (float)ix;
        float fy = y - (float)iy;

        int idx = iy * RST + ix - Koff;
        if (!interior) idx = min(max(idx, 0), IDXMAX);  // v_med3; masked px safe

        const unsigned int* lp = smw + idx;     // ONE vaddr, 4x ds_read2_b32
        unsigned iA0 = lp[0],  iA1 = lp[1];     // top {c0,c1} L,R
        unsigned iB0 = lp[25], iB1 = lp[26];    // top {c2,0}  L,R
        unsigned iA2 = lp[51], iA3 = lp[52];    // bot {c0,c1} L,R
        unsigned iB2 = lp[76], iB3 = lp[77];    // bot {c2,0}  L,R

        __half2 fx2 = __float2half2_rn(fx);
        __half2 fy2 = __float2half2_rn(fy);
        __half2 a01 = *(const __half2*)&iA0, c01 = *(const __half2*)&iA1;
        __half2 a2  = *(const __half2*)&iB0, c2  = *(const __half2*)&iB1;
        __half2 b01 = *(const __half2*)&iA2, d01 = *(const __half2*)&iA3;
        __half2 b2  = *(const __half2*)&iB2, d2  = *(const __half2*)&iB3;

        __half2 t01 = __hfma2(fx2, __hsub2(c01, a01), a01);   // top lerp
        __half2 t2  = __hfma2(fx2, __hsub2(c2,  a2),  a2);
        __half2 u01 = __hfma2(fx2, __hsub2(d01, b01), b01);   // bottom lerp
        __half2 u2  = __hfma2(fx2, __hsub2(d2,  b2),  b2);
        __half2 r01 = __hfma2(fy2, __hsub2(u01, t01), t01);   // vertical
        __half2 r2  = __hfma2(fy2, __hsub2(u2,  t2),  t2);

        float v0 = __low2float(r01);
        float v1 = __high2float(r01);
        float v2 = __low2float(r2);
        if (!interior) {
            // Reference yields exactly 0 where clamped corners collapse
            // (x<0, x>=511, y<0, y>=511).
            bool valid = ((unsigned)ix < 511u) & ((unsigned)iy < 511u);
            v0 = valid ? v0 : 0.0f;
            v1 = valid ? v1 : 0.0f;
            v2 = valid ? v2 : 0.0f;
        }
        o[p * 3 + 0] = v0;
        o[p * 3 + 1] = v1;
        o[p * 3 + 2] = v2;
    }

    // 4 px = 48 B contiguous, 16B-aligned.
    float* po = out + (((size_t)b * OUT_H + (i0 + il)) * OUT_W + (j0 + jb2)) * CHANS;
    ((float4*)po)[0] = make_float4(o[0], o[1], o[2],  o[3]);
    ((float4*)po)[1] = make_float4(o[4], o[5], o[6],  o[7]);
    ((float4*)po)[2] = make_float4(o[8], o[9], o[10], o[11]);
}

extern "C" void kernel_launch(void* const* d_in, const int* in_sizes, int n_in,
                              void* d_out, int out_size, void* d_ws, size_t ws_size,
                              hipStream_t stream) {
    const float* U     = (const float*)d_in[0];
    const float* theta = (const float*)d_in[1];
    float* out = (float*)d_out;

    int blocks = BATCH * 256;           // 64 images x 256 blocks (4 waves x 16x16 tiles)
    st_bilinear_kernel<<<blocks, 256, 0, stream>>>(U, theta, out);
}